// Round 9
// baseline (450.545 us; speedup 1.0000x reference)
//
#include <hip/hip_runtime.h>
#include <hip/hip_bf16.h>

// CPCA_Weighted: T=256 N=8 H=512 K=16 A=4, 7 actions, P_SUB=0.1, LOSS_FACTOR=0.1
// R9 = R8 resubmit (infra failure last round): conflict-free LDS layouts,
// 2-phase stage overlap, cls fused into gru_main, k-split projP in prep.
#define T_DIM 256
#define KK    16

typedef __attribute__((ext_vector_type(8))) short bf16x8;
typedef __attribute__((ext_vector_type(4))) float f32x4;

#define MFMA16(A, B, C) __builtin_amdgcn_mfma_f32_16x16x32_bf16(A, B, C, 0, 0, 0)
#define SLOT 1048576   // shorts per h slot (2048 seqs x 512)

__device__ __forceinline__ unsigned short f2b(float x) {
  unsigned u = __float_as_uint(x);
  unsigned r = (u + 0x7FFFu + ((u >> 16) & 1u)) >> 16;   // RNE
  return (unsigned short)r;
}

// ---- L3-coherent ops for cross-wg communication (verified R5-R7) -------------
__device__ __forceinline__ bf16x8 ld_b128_bypass(const unsigned short* p) {
  bf16x8 r;
  asm volatile("global_load_dwordx4 %0, %1, off sc0 sc1" : "=v"(r) : "v"(p) : "memory");
  return r;
}
__device__ __forceinline__ void st_b128_bypass(unsigned short* p, bf16x8 v) {
  asm volatile("global_store_dwordx4 %0, %1, off sc0 sc1" :: "v"(p), "v"(v) : "memory");
}
__device__ __forceinline__ unsigned ld_u32_bypass(const unsigned* p) {
  unsigned r;
  asm volatile("global_load_dword %0, %1, off sc0 sc1\n\ts_waitcnt vmcnt(0)"
               : "=v"(r) : "v"(p) : "memory");
  return r;
}
__device__ __forceinline__ bf16x8 ld_b128(const unsigned short* p) {
  bf16x8 r;
  asm volatile("global_load_dwordx4 %0, %1, off" : "=v"(r) : "v"(p) : "memory");
  return r;
}
#define WAITVM0() asm volatile("s_waitcnt vmcnt(0)" ::: "memory")

// JAX threefry2x32 (20 rounds)
__device__ __forceinline__ void tf2x32(unsigned k0, unsigned k1, unsigned x0, unsigned x1,
                                       unsigned &o0, unsigned &o1) {
  unsigned ks2 = k0 ^ k1 ^ 0x1BD11BDAu;
  x0 += k0; x1 += k1;
#define TFR(R) { x0 += x1; x1 = (x1 << R) | (x1 >> (32 - R)); x1 ^= x0; }
  TFR(13) TFR(15) TFR(26) TFR(6)   x0 += k1;  x1 += ks2 + 1u;
  TFR(17) TFR(29) TFR(16) TFR(24)  x0 += ks2; x1 += k0 + 2u;
  TFR(13) TFR(15) TFR(26) TFR(6)   x0 += k0;  x1 += k1 + 3u;
  TFR(17) TFR(29) TFR(16) TFR(24)  x0 += k1;  x1 += ks2 + 4u;
  TFR(13) TFR(15) TFR(26) TFR(6)   x0 += ks2; x1 += k0 + 5u;
#undef TFR
  o0 = x0; o1 = x1;
}

// ---- prep ---------------------------------------------------------------------
__global__ void prep(const float* __restrict__ W_hh, const float* __restrict__ W1,
                     const float* __restrict__ emb,  const float* __restrict__ W_ih,
                     const float* __restrict__ b_ih, const float* __restrict__ b_hh,
                     const float* __restrict__ vision, const int* __restrict__ env_zeros,
                     const float* __restrict__ belief,
                     unsigned short* __restrict__ wBf, unsigned short* __restrict__ wQf,
                     float* __restrict__ girz, float* __restrict__ gin,
                     float* __restrict__ projP, unsigned char* __restrict__ maskb,
                     unsigned short* __restrict__ hbS, unsigned* __restrict__ cnt) {
  int b = blockIdx.x, tid = threadIdx.x;
  if (b < 768) {                               // wBf swizzle: coalesced read W_hh
    int idx = b * 256 + tid;
    int row = idx >> 7, k4 = (idx & 127) << 2;
    float4 v = *(const float4*)(W_hh + ((size_t)row << 9) + k4);
    int gam = row >> 9, sl = (row >> 6) & 7, q = (row >> 4) & 3, col0 = row & 15;
    int kt = k4 >> 5, quad = (k4 >> 3) & 3, e = k4 & 7;
    int F = (sl * 12 + gam * 4 + q) * 16 + kt;
    ushort4 o; o.x = f2b(v.x); o.y = f2b(v.y); o.z = f2b(v.z); o.w = f2b(v.w);
    *(ushort4*)(wBf + ((size_t)F << 9) + ((quad * 16 + col0) << 3) + e) = o;
  } else if (b < 784) {                        // wQf swizzle
    int idx = (b - 768) * 256 + tid;
    int f = idx >> 7, k4 = (idx & 127) << 2;
    float4 v = *(const float4*)(W1 + (size_t)f * 1024 + 512 + k4);
    int ft = f >> 4, col0 = f & 15;
    int kt = k4 >> 5, quad = (k4 >> 3) & 3, e = k4 & 7;
    int F = ft * 16 + kt;
    ushort4 o; o.x = f2b(v.x); o.y = f2b(v.y); o.z = f2b(v.z); o.w = f2b(v.w);
    *(ushort4*)(wQf + ((size_t)F << 9) + ((quad * 16 + col0) << 3) + e) = o;
  } else if (b < 816) {                        // girz[gam*8+a][512]
    int idx = (b - 784) * 256 + tid;
    int c = idx & 511, ga = idx >> 9;
    int a = ga & 7, gam = ga >> 3;
    float s = b_ih[gam * 512 + c] + b_hh[gam * 512 + c];
    if (a < 7) {
      #pragma unroll
      for (int k = 0; k < 4; ++k) s += emb[a * 4 + k] * W_ih[(gam * 512 + c) * 4 + k];
    }
    girz[idx] = s;
  } else if (b < 832) {                        // gin[a][512] = i_n (no b_hh)
    int idx = (b - 816) * 256 + tid;
    int c = idx & 511, a = idx >> 9;
    float s = b_ih[1024 + c];
    if (a < 7) {
      #pragma unroll
      for (int k = 0; k < 4; ++k) s += emb[a * 4 + k] * W_ih[(1024 + c) * 4 + k];
    }
    gin[idx] = s;
  } else if (b < 896) {                        // masks: legacy JAX threefry
    int i = (b - 832) * 256 + tid;
    unsigned a0, b0, a1, b1_;
    tf2x32(0u, 42u, 0u, 2u, a0, b0);
    tf2x32(0u, 42u, 1u, 3u, a1, b1_);
    unsigned p0, p1, n0, n1;
    tf2x32(a0, a1, (unsigned)i, (unsigned)(i + 16384), p0, p1);
    tf2x32(b0, b1_, (unsigned)i, (unsigned)(i + 16384), n0, n1);
    #pragma unroll
    for (int h = 0; h < 2; ++h) {
      int f = i + h * 16384;
      unsigned pw = h ? p1 : p0, nw = h ? n1 : n0;
      int t = f >> 7, j = (f >> 3) & 15, nn = f & 7;
      int ok = (t + j < T_DIM - 1);
      if (ok) {
        int lo = t + 1, hi = t + j + 1, hit = 0;
        #pragma unroll
        for (int q = 0; q < 4; ++q) { int z = env_zeros[nn * 4 + q]; hit |= (z >= lo && z <= hi); }
        ok = !hit;
      }
      unsigned sp = ((pw >> 9) < 0xCCCCDu) ? 1u : 0u;
      unsigned sn = ((nw >> 9) < 0xCCCCDu) ? 2u : 0u;
      maskb[f] = ok ? (unsigned char)(sp | sn) : (unsigned char)0;
    }
  } else if (b == 896) {                       // zero barrier counters
    for (int i = tid; i < 1024; i += 256) cnt[i] = 0u;
  } else if (b < 1409) {                       // slot0: belief -> kt-major A-frags
    int i = (b - 897) * 256 + tid;             // [0, 131072)
    int f = i >> 6, l = i & 63;
    int f2 = f & 63;
    int seq = (f >> 6) * 64 + (f2 & 3) * 16 + (l & 15);
    int kb = (f2 >> 2) * 32 + (l >> 4) * 8;
    const float* src = belief + (size_t)seq * 512 + kb;
    float4 v0 = *(const float4*)src, v1 = *(const float4*)(src + 4);
    bf16x8 o;
    o[0] = (short)f2b(v0.x); o[1] = (short)f2b(v0.y); o[2] = (short)f2b(v0.z); o[3] = (short)f2b(v0.w);
    o[4] = (short)f2b(v1.x); o[5] = (short)f2b(v1.y); o[6] = (short)f2b(v1.z); o[7] = (short)f2b(v1.w);
    *(bf16x8*)&hbS[((size_t)f << 9) + l * 8] = o;
  } else {                                     // projP: k-split, block = one seq
    __shared__ float red[32][9];
    int s = b - 1409;                          // [0, 2048)
    int f = tid & 31, kc = tid >> 5;           // 8 k-chunks of 64
    const float4* wr = (const float4*)(W1 + (size_t)f * 1024 + kc * 64);
    const float4* vr = (const float4*)(vision + (size_t)s * 512 + kc * 64);
    float acc = 0.f;
    #pragma unroll
    for (int i = 0; i < 16; ++i) {
      float4 wv = wr[i], vv = vr[i];
      acc += wv.x * vv.x + wv.y * vv.y + wv.z * vv.z + wv.w * vv.w;
    }
    red[f][kc] = acc;
    __syncthreads();
    if (kc == 0) {
      float t = 0.f;
      #pragma unroll
      for (int q = 0; q < 8; ++q) t += red[f][q];
      projP[s * 32 + f] = t;
    }
  }
}

// ---- persistent GRU + fused cls ----------------------------------------------
__global__ __launch_bounds__(384, 1) void gru_main(
    const float* __restrict__ belief, const int* __restrict__ actions,
    const float* __restrict__ b_hh, const unsigned short* __restrict__ wBf,
    const float* __restrict__ girz, const float* __restrict__ gin,
    unsigned short* __restrict__ hbS, unsigned* __restrict__ cnt,
    const unsigned short* __restrict__ wQf, const int* __restrict__ neg_inds,
    const float* __restrict__ b1, const float* __restrict__ W2,
    const float* __restrict__ b2, const float* __restrict__ projP,
    const unsigned char* __restrict__ maskb, float* __restrict__ parts) {
  __shared__ unsigned short sA[64 * 512];      // 65536B, kt-major frags
  __shared__ float accL2[12672];               // 50688B: [(gam*4+a)*16+m][66]
  __shared__ unsigned short bounce[64 * 74];   // 9472B
  __shared__ float hpL[64 * 66];               // 16896B
  // total 142592B -> 1 wg/CU by LDS

  const int tid = threadIdx.x, w = tid >> 6, lane = tid & 63;
  const int b = blockIdx.x;
  const int sl = b >> 5, g = b & 31;
  const int c0 = sl * 64, seqbase = g * 64;
  const int col0 = lane & 15, quad = lane >> 4;

  // B fragments: 2 N-tiles per wave, register-resident
  bf16x8 bB[32];
  {
    const unsigned short* p0 = wBf + ((size_t)((sl * 12 + 2 * w) * 16) << 9) + lane * 8;
    #pragma unroll
    for (int kt = 0; kt < 32; ++kt) bB[kt] = ld_b128(p0 + ((size_t)kt << 9));
    WAITVM0();
  }

  // hp init: thread owns (s = 6k+w, c = lane)
  #pragma unroll
  for (int k = 0; k < 11; ++k) {
    int s = 6 * k + w;
    if (s < 64) hpL[s * 66 + lane] = belief[((size_t)(seqbase + s) << 9) + c0 + lane];
  }

  // cls constants + accumulators (used by wave 0 of slices 0-3)
  const float b1v0 = b1[col0], b1v1 = b1[col0 + 16];
  const float w2v0 = W2[col0], w2v1 = W2[col0 + 16], b2v = b2[0];
  float sumP = 0.f, cntP = 0.f, sumN = 0.f, cntN = 0.f;

  for (int j = 0; j <= KK; ++j) {
    if (j > 0) {                               // group barrier
      if (tid == 0) {
        const unsigned tgt = 8u * (unsigned)j;
        while (ld_u32_bypass(cnt + g * 32) < tgt) __builtin_amdgcn_s_sleep(2);
      }
      __syncthreads();
    }
    const unsigned short* src = hbS + (size_t)j * SLOT + ((size_t)(g * 64) << 9);
    // stage phase 1: lines 0..2047 (kt 0..7)
    {
      bf16x8 u0 = ld_b128_bypass(src + ((size_t)(tid)        << 3));
      bf16x8 u1 = ld_b128_bypass(src + ((size_t)(tid + 384)  << 3));
      bf16x8 u2 = ld_b128_bypass(src + ((size_t)(tid + 768)  << 3));
      bf16x8 u3 = ld_b128_bypass(src + ((size_t)(tid + 1152) << 3));
      bf16x8 u4 = ld_b128_bypass(src + ((size_t)(tid + 1536) << 3));
      bf16x8 u5; const bool ex = (tid < 128);
      if (ex) u5 = ld_b128_bypass(src + ((size_t)(tid + 1920) << 3));
      WAITVM0();
      *(bf16x8*)&sA[(size_t)(tid)        << 3] = u0;
      *(bf16x8*)&sA[(size_t)(tid + 384)  << 3] = u1;
      *(bf16x8*)&sA[(size_t)(tid + 768)  << 3] = u2;
      *(bf16x8*)&sA[(size_t)(tid + 1152) << 3] = u3;
      *(bf16x8*)&sA[(size_t)(tid + 1536) << 3] = u4;
      if (ex) *(bf16x8*)&sA[(size_t)(tid + 1920) << 3] = u5;
    }
    // issue phase-2 loads (fly during GEMM part 1)
    bf16x8 v0 = ld_b128_bypass(src + ((size_t)(tid + 2048) << 3));
    bf16x8 v1 = ld_b128_bypass(src + ((size_t)(tid + 2432) << 3));
    bf16x8 v2 = ld_b128_bypass(src + ((size_t)(tid + 2816) << 3));
    bf16x8 v3 = ld_b128_bypass(src + ((size_t)(tid + 3200) << 3));
    bf16x8 v4 = ld_b128_bypass(src + ((size_t)(tid + 3584) << 3));
    bf16x8 v5; const bool ex2 = (tid < 128);
    if (ex2) v5 = ld_b128_bypass(src + ((size_t)(tid + 3968) << 3));
    __syncthreads();

    f32x4 acc[4][2];
    #pragma unroll
    for (int a = 0; a < 4; ++a) { acc[a][0] = (f32x4){0,0,0,0}; acc[a][1] = (f32x4){0,0,0,0}; }
    if (j < KK) {                              // GEMM part 1: kt 0..7
      #pragma unroll
      for (int kt = 0; kt < 8; ++kt) {
        #pragma unroll
        for (int a = 0; a < 4; ++a) {
          bf16x8 af = *(const bf16x8*)&sA[(((kt * 4 + a)) << 9) + (lane << 3)];
          acc[a][0] = MFMA16(af, bB[kt], acc[a][0]);
          acc[a][1] = MFMA16(af, bB[16 + kt], acc[a][1]);
        }
      }
    }
    WAITVM0();                                 // phase-2 data arrived
    *(bf16x8*)&sA[(size_t)(tid + 2048) << 3] = v0;
    *(bf16x8*)&sA[(size_t)(tid + 2432) << 3] = v1;
    *(bf16x8*)&sA[(size_t)(tid + 2816) << 3] = v2;
    *(bf16x8*)&sA[(size_t)(tid + 3200) << 3] = v3;
    *(bf16x8*)&sA[(size_t)(tid + 3584) << 3] = v4;
    if (ex2) *(bf16x8*)&sA[(size_t)(tid + 3968) << 3] = v5;
    __syncthreads();

    if (j < KK) {
      #pragma unroll
      for (int kt = 8; kt < 16; ++kt) {        // GEMM part 2: kt 8..15
        #pragma unroll
        for (int a = 0; a < 4; ++a) {
          bf16x8 af = *(const bf16x8*)&sA[(((kt * 4 + a)) << 9) + (lane << 3)];
          acc[a][0] = MFMA16(af, bB[kt], acc[a][0]);
          acc[a][1] = MFMA16(af, bB[16 + kt], acc[a][1]);
        }
      }
      // publish accs, conflict-free scalar layout
      #pragma unroll
      for (int t2 = 0; t2 < 2; ++t2) {
        int nu = w * 2 + t2, gam = nu >> 2, q = nu & 3;
        #pragma unroll
        for (int a = 0; a < 4; ++a)
          #pragma unroll
          for (int r = 0; r < 4; ++r)
            accL2[((gam * 4 + a) * 16 + quad * 4 + r) * 66 + q * 16 + col0] = acc[a][t2][r];
      }
      __syncthreads();
      // balanced epilogue: (s = 6k+w, c = lane)
      #pragma unroll
      for (int k = 0; k < 11; ++k) {
        int s = 6 * k + w;
        if (s < 64) {
          int c = lane, a = s >> 4, m = s & 15;
          int cc = c0 + c;
          float aR = accL2[((a) * 16 + m) * 66 + c];
          float aZ = accL2[((4 + a) * 16 + m) * 66 + c];
          float aN = accL2[((8 + a) * 16 + m) * 66 + c];
          int seq = seqbase + s;
          int tr = seq >> 3, nn = seq & 7, tj = tr + j;
          int ai = (tj < T_DIM) ? actions[tj * 8 + nn] : 7;
          float rg = 1.f / (1.f + __expf(-(aR + girz[(ai << 9) + cc])));
          float zg = 1.f / (1.f + __expf(-(aZ + girz[((8 + ai) << 9) + cc])));
          float pre = gin[(ai << 9) + cc] + rg * (aN + b_hh[1024 + cc]);
          float cand = 1.f - 2.f / (1.f + __expf(2.f * pre));
          float hn = (1.f - zg) * cand + zg * hpL[s * 66 + c];
          hpL[s * 66 + c] = hn;
          bounce[s * 74 + c] = f2b(hn);
        }
      }
      __syncthreads();
      // publish our slice's h_{j+1} frags (kt = 2sl+ktl) to slot j+1
      unsigned short* dst = hbS + (size_t)(j + 1) * SLOT;
      {
        int f = tid >> 6, l = tid & 63;        // f in 0..5
        int a = f >> 1, ktl = f & 1;
        bf16x8 vv = *(const bf16x8*)&bounce[(16 * a + (l & 15)) * 74 + 32 * ktl + (l >> 4) * 8];
        st_b128_bypass(&dst[((size_t)(g * 64 + (2 * sl + ktl) * 4 + a) << 9) + (l << 3)], vv);
        if (tid < 128) {
          int i2 = tid + 384;
          int f2 = i2 >> 6, l2 = i2 & 63;
          int a2 = f2 >> 1, ktl2 = f2 & 1;
          bf16x8 v2b = *(const bf16x8*)&bounce[(16 * a2 + (l2 & 15)) * 74 + 32 * ktl2 + (l2 >> 4) * 8];
          st_b128_bypass(&dst[((size_t)(g * 64 + (2 * sl + ktl2) * 4 + a2) << 9) + (l2 << 3)], v2b);
        }
      }
      WAITVM0();
      __syncthreads();
      if (tid == 0) atomicAdd(cnt + g * 32, 1u);
    }

    // fused classifier for jq = j-1 (wave 0, slices 0-3; sA = h_j intact)
    if (j >= 1 && sl < 4 && w == 0) {
      const int jq = j - 1, a = sl;
      const unsigned short* qp = wQf + lane * 8;
      f32x4 ca0 = {0,0,0,0}, ca1 = {0,0,0,0};
      #pragma unroll
      for (int kt = 0; kt < 16; ++kt) {
        bf16x8 af = *(const bf16x8*)&sA[((kt * 4 + a) << 9) + (lane << 3)];
        ca0 = MFMA16(af, *(const bf16x8*)(qp + ((size_t)kt << 9)), ca0);
        ca1 = MFMA16(af, *(const bf16x8*)(qp + ((size_t)(16 + kt) << 9)), ca1);
      }
      float wj = (jq == 0) ? 5.f : (jq == 1) ? 4.f : (jq < 4) ? 3.f : (jq < 8) ? 2.f : 1.f;
      #pragma unroll
      for (int r = 0; r < 4; ++r) {
        int seq = seqbase + 16 * a + quad * 4 + r;
        int t = seq >> 3, nn = seq & 7;
        unsigned mb = maskb[(t << 7) + (jq << 3) + nn];
        float pp0 = 0.f, pp1 = 0.f, pn0 = 0.f, pn1 = 0.f;
        if (mb) {
          int sp = seq + j * 8;
          pp0 = projP[(sp << 5) + col0];  pp1 = projP[(sp << 5) + 16 + col0];
          int ni = neg_inds[sp];
          pn0 = projP[(ni << 5) + col0];  pn1 = projP[(ni << 5) + 16 + col0];
        }
        float a0v = ca0[r] + b1v0, a1v = ca1[r] + b1v1;
        float pl = fmaxf(a0v + pp0, 0.f) * w2v0 + fmaxf(a1v + pp1, 0.f) * w2v1;
        float nl = fmaxf(a0v + pn0, 0.f) * w2v0 + fmaxf(a1v + pn1, 0.f) * w2v1;
        #pragma unroll
        for (int d = 1; d < 16; d <<= 1) { pl += __shfl_xor(pl, d, 64); nl += __shfl_xor(nl, d, 64); }
        if (col0 == 0 && mb) {
          if (mb & 1u) {
            float x = -(pl + b2v);
            sumP += wj * (fmaxf(x, 0.f) + __logf(1.f + __expf(-fabsf(x))));
            cntP += 1.f;
          }
          if (mb & 2u) {
            float x = (nl + b2v);
            sumN += wj * (fmaxf(x, 0.f) + __logf(1.f + __expf(-fabsf(x))));
            cntN += 1.f;
          }
        }
      }
    }
  }

  if (sl < 4 && w == 0) {                      // finalize this wg's loss partials
    #pragma unroll
    for (int d = 16; d < 64; d <<= 1) {
      sumP += __shfl_xor(sumP, d, 64); cntP += __shfl_xor(cntP, d, 64);
      sumN += __shfl_xor(sumN, d, 64); cntN += __shfl_xor(cntN, d, 64);
    }
    if (lane == 0) {
      float4 o; o.x = sumP; o.y = cntP; o.z = sumN; o.w = cntN;
      *(float4*)&parts[(sl * 32 + g) * 4] = o;
    }
  }
}

__global__ __launch_bounds__(256, 1) void fin(const float* __restrict__ parts,
                                              float* __restrict__ out) {
  __shared__ float red[4][4];
  const int tid = threadIdx.x;
  float v0 = 0.f, v1 = 0.f, v2 = 0.f, v3 = 0.f;
  if (tid < 128) {
    v0 = parts[tid * 4 + 0]; v1 = parts[tid * 4 + 1];
    v2 = parts[tid * 4 + 2]; v3 = parts[tid * 4 + 3];
  }
  #pragma unroll
  for (int d = 1; d < 64; d <<= 1) {
    v0 += __shfl_xor(v0, d, 64); v1 += __shfl_xor(v1, d, 64);
    v2 += __shfl_xor(v2, d, 64); v3 += __shfl_xor(v3, d, 64);
  }
  if ((tid & 63) == 0) {
    int w = tid >> 6;
    red[w][0] = v0; red[w][1] = v1; red[w][2] = v2; red[w][3] = v3;
  }
  __syncthreads();
  if (tid == 0) {
    float sP = red[0][0] + red[1][0] + red[2][0] + red[3][0];
    float cP = red[0][1] + red[1][1] + red[2][1] + red[3][1];
    float sN = red[0][2] + red[1][2] + red[2][2] + red[3][2];
    float cN = red[0][3] + red[1][3] + red[2][3] + red[3][3];
    out[0] = (sP / fmaxf(cP, 1.f) + sN / fmaxf(cN, 1.f)) * 0.1f;
  }
}

extern "C" void kernel_launch(void* const* d_in, const int* in_sizes, int n_in,
                              void* d_out, int out_size, void* d_ws, size_t ws_size,
                              hipStream_t stream) {
  const float* vision  = (const float*)d_in[0];
  const float* belief  = (const float*)d_in[1];
  const int*   actions = (const int*)d_in[2];
  const int*   envz    = (const int*)d_in[3];
  const int*   negi    = (const int*)d_in[4];
  const float* emb     = (const float*)d_in[5];
  const float* W_ih    = (const float*)d_in[6];
  const float* W_hh    = (const float*)d_in[7];
  const float* b_ih    = (const float*)d_in[8];
  const float* b_hh    = (const float*)d_in[9];
  const float* W1      = (const float*)d_in[10];
  const float* b1      = (const float*)d_in[11];
  const float* W2      = (const float*)d_in[12];
  const float* b2      = (const float*)d_in[13];

  char* ws = (char*)d_ws;
  unsigned*       cnt   = (unsigned*)(ws + 0);               // 1024 ints (4KB)
  float*          parts = (float*)(ws + 4096);               // 128 x 4 floats
  unsigned short* wBf   = (unsigned short*)(ws + 12288);     // 1572864 B
  unsigned short* wQf   = (unsigned short*)(ws + 1585152);   // 32768 B
  float*          girz  = (float*)(ws + 1617920);            // 32768 B
  float*          gin   = (float*)(ws + 1650688);            // 16384 B
  float*          projP = (float*)(ws + 1667072);            // 262144 B
  unsigned char*  maskb = (unsigned char*)(ws + 1929216);    // 32768 B
  unsigned short* hbS   = (unsigned short*)(ws + 1961984);   // 17 x 2097152 B

  prep<<<3457, 256, 0, stream>>>(W_hh, W1, emb, W_ih, b_ih, b_hh, vision, envz,
                                 belief, wBf, wQf, girz, gin, projP, maskb,
                                 hbS, cnt);
  gru_main<<<256, 384, 0, stream>>>(belief, actions, b_hh, wBf, girz, gin,
                                    hbS, cnt, wQf, negi, b1, W2, b2, projP,
                                    maskb, parts);
  fin<<<1, 256, 0, stream>>>(parts, (float*)d_out);
}

// Round 10
// 274.278 us; speedup vs baseline: 1.6427x; 1.6427x over previous
//
#include <hip/hip_runtime.h>
#include <hip/hip_bf16.h>

// CPCA_Weighted: T=256 N=8 H=512 K=16 A=4, 7 actions, P_SUB=0.1, LOSS_FACTOR=0.1
// R10 = R7 core (persistent 256x384, B reg-resident, L3 exchange, separate cls)
// + conflict-free LDS layouts (accL2/bounce74/hpL66) + k-split projP prep.
#define T_DIM 256
#define KK    16

typedef __attribute__((ext_vector_type(8))) short bf16x8;
typedef __attribute__((ext_vector_type(4))) float f32x4;

#define MFMA16(A, B, C) __builtin_amdgcn_mfma_f32_16x16x32_bf16(A, B, C, 0, 0, 0)
#define SLOT 1048576   // shorts per h slot (2048 seqs x 512)

__device__ __forceinline__ unsigned short f2b(float x) {
  unsigned u = __float_as_uint(x);
  unsigned r = (u + 0x7FFFu + ((u >> 16) & 1u)) >> 16;   // RNE
  return (unsigned short)r;
}

// ---- L3-coherent ops for cross-wg communication (verified R5-R7) -------------
__device__ __forceinline__ bf16x8 ld_b128_bypass(const unsigned short* p) {
  bf16x8 r;
  asm volatile("global_load_dwordx4 %0, %1, off sc0 sc1" : "=v"(r) : "v"(p) : "memory");
  return r;
}
__device__ __forceinline__ void st_b128_bypass(unsigned short* p, bf16x8 v) {
  asm volatile("global_store_dwordx4 %0, %1, off sc0 sc1" :: "v"(p), "v"(v) : "memory");
}
__device__ __forceinline__ unsigned ld_u32_bypass(const unsigned* p) {
  unsigned r;
  asm volatile("global_load_dword %0, %1, off sc0 sc1\n\ts_waitcnt vmcnt(0)"
               : "=v"(r) : "v"(p) : "memory");
  return r;
}
__device__ __forceinline__ bf16x8 ld_b128(const unsigned short* p) {
  bf16x8 r;
  asm volatile("global_load_dwordx4 %0, %1, off" : "=v"(r) : "v"(p) : "memory");
  return r;
}
#define WAITVM0() asm volatile("s_waitcnt vmcnt(0)" ::: "memory")

// JAX threefry2x32 (20 rounds)
__device__ __forceinline__ void tf2x32(unsigned k0, unsigned k1, unsigned x0, unsigned x1,
                                       unsigned &o0, unsigned &o1) {
  unsigned ks2 = k0 ^ k1 ^ 0x1BD11BDAu;
  x0 += k0; x1 += k1;
#define TFR(R) { x0 += x1; x1 = (x1 << R) | (x1 >> (32 - R)); x1 ^= x0; }
  TFR(13) TFR(15) TFR(26) TFR(6)   x0 += k1;  x1 += ks2 + 1u;
  TFR(17) TFR(29) TFR(16) TFR(24)  x0 += ks2; x1 += k0 + 2u;
  TFR(13) TFR(15) TFR(26) TFR(6)   x0 += k0;  x1 += k1 + 3u;
  TFR(17) TFR(29) TFR(16) TFR(24)  x0 += k1;  x1 += ks2 + 4u;
  TFR(13) TFR(15) TFR(26) TFR(6)   x0 += ks2; x1 += k0 + 5u;
#undef TFR
  o0 = x0; o1 = x1;
}

// ---- prep ---------------------------------------------------------------------
__global__ void prep(const float* __restrict__ W_hh, const float* __restrict__ W1,
                     const float* __restrict__ emb,  const float* __restrict__ W_ih,
                     const float* __restrict__ b_ih, const float* __restrict__ b_hh,
                     const float* __restrict__ vision, const int* __restrict__ env_zeros,
                     const float* __restrict__ belief,
                     unsigned short* __restrict__ wBf, unsigned short* __restrict__ wQf,
                     float* __restrict__ girz, float* __restrict__ gin,
                     float* __restrict__ projP, unsigned char* __restrict__ maskb,
                     unsigned short* __restrict__ hbS, unsigned* __restrict__ cnt) {
  int b = blockIdx.x, tid = threadIdx.x;
  if (b < 768) {                               // wBf swizzle: coalesced read W_hh
    int idx = b * 256 + tid;
    int row = idx >> 7, k4 = (idx & 127) << 2;
    float4 v = *(const float4*)(W_hh + ((size_t)row << 9) + k4);
    int gam = row >> 9, sl = (row >> 6) & 7, q = (row >> 4) & 3, col0 = row & 15;
    int kt = k4 >> 5, quad = (k4 >> 3) & 3, e = k4 & 7;
    int F = (sl * 12 + gam * 4 + q) * 16 + kt;
    ushort4 o; o.x = f2b(v.x); o.y = f2b(v.y); o.z = f2b(v.z); o.w = f2b(v.w);
    *(ushort4*)(wBf + ((size_t)F << 9) + ((quad * 16 + col0) << 3) + e) = o;
  } else if (b < 784) {                        // wQf swizzle
    int idx = (b - 768) * 256 + tid;
    int f = idx >> 7, k4 = (idx & 127) << 2;
    float4 v = *(const float4*)(W1 + (size_t)f * 1024 + 512 + k4);
    int ft = f >> 4, col0 = f & 15;
    int kt = k4 >> 5, quad = (k4 >> 3) & 3, e = k4 & 7;
    int F = ft * 16 + kt;
    ushort4 o; o.x = f2b(v.x); o.y = f2b(v.y); o.z = f2b(v.z); o.w = f2b(v.w);
    *(ushort4*)(wQf + ((size_t)F << 9) + ((quad * 16 + col0) << 3) + e) = o;
  } else if (b < 816) {                        // girz[gam*8+a][512]
    int idx = (b - 784) * 256 + tid;
    int c = idx & 511, ga = idx >> 9;
    int a = ga & 7, gam = ga >> 3;
    float s = b_ih[gam * 512 + c] + b_hh[gam * 512 + c];
    if (a < 7) {
      #pragma unroll
      for (int k = 0; k < 4; ++k) s += emb[a * 4 + k] * W_ih[(gam * 512 + c) * 4 + k];
    }
    girz[idx] = s;
  } else if (b < 832) {                        // gin[a][512] = i_n (no b_hh)
    int idx = (b - 816) * 256 + tid;
    int c = idx & 511, a = idx >> 9;
    float s = b_ih[1024 + c];
    if (a < 7) {
      #pragma unroll
      for (int k = 0; k < 4; ++k) s += emb[a * 4 + k] * W_ih[(1024 + c) * 4 + k];
    }
    gin[idx] = s;
  } else if (b < 896) {                        // masks: legacy JAX threefry
    int i = (b - 832) * 256 + tid;
    unsigned a0, b0, a1, b1_;
    tf2x32(0u, 42u, 0u, 2u, a0, b0);
    tf2x32(0u, 42u, 1u, 3u, a1, b1_);
    unsigned p0, p1, n0, n1;
    tf2x32(a0, a1, (unsigned)i, (unsigned)(i + 16384), p0, p1);
    tf2x32(b0, b1_, (unsigned)i, (unsigned)(i + 16384), n0, n1);
    #pragma unroll
    for (int h = 0; h < 2; ++h) {
      int f = i + h * 16384;
      unsigned pw = h ? p1 : p0, nw = h ? n1 : n0;
      int t = f >> 7, j = (f >> 3) & 15, nn = f & 7;
      int ok = (t + j < T_DIM - 1);
      if (ok) {
        int lo = t + 1, hi = t + j + 1, hit = 0;
        #pragma unroll
        for (int q = 0; q < 4; ++q) { int z = env_zeros[nn * 4 + q]; hit |= (z >= lo && z <= hi); }
        ok = !hit;
      }
      unsigned sp = ((pw >> 9) < 0xCCCCDu) ? 1u : 0u;
      unsigned sn = ((nw >> 9) < 0xCCCCDu) ? 2u : 0u;
      maskb[f] = ok ? (unsigned char)(sp | sn) : (unsigned char)0;
    }
  } else if (b == 896) {                       // zero barrier counters
    for (int i = tid; i < 1024; i += 256) cnt[i] = 0u;
  } else if (b < 1409) {                       // slot0: belief -> a-major A-frags
    int i = (b - 897) * 256 + tid;             // [0, 131072)
    int f = i >> 6, l = i & 63;
    int seq = (f >> 4) * 16 + (l & 15);
    int kb = (f & 15) * 32 + (l >> 4) * 8;
    const float* src = belief + (size_t)seq * 512 + kb;
    float4 v0 = *(const float4*)src, v1 = *(const float4*)(src + 4);
    bf16x8 o;
    o[0] = (short)f2b(v0.x); o[1] = (short)f2b(v0.y); o[2] = (short)f2b(v0.z); o[3] = (short)f2b(v0.w);
    o[4] = (short)f2b(v1.x); o[5] = (short)f2b(v1.y); o[6] = (short)f2b(v1.z); o[7] = (short)f2b(v1.w);
    *(bf16x8*)&hbS[((size_t)f << 9) + l * 8] = o;
  } else {                                     // projP: k-split, block = one seq
    __shared__ float red[32][9];
    int s = b - 1409;                          // [0, 2048)
    int f = tid & 31, kc = tid >> 5;           // 8 k-chunks of 64
    const float4* wr = (const float4*)(W1 + (size_t)f * 1024 + kc * 64);
    const float4* vr = (const float4*)(vision + (size_t)s * 512 + kc * 64);
    float acc = 0.f;
    #pragma unroll
    for (int i = 0; i < 16; ++i) {
      float4 wv = wr[i], vv = vr[i];
      acc += wv.x * vv.x + wv.y * vv.y + wv.z * vv.z + wv.w * vv.w;
    }
    red[f][kc] = acc;
    __syncthreads();
    if (kc == 0) {
      float t = 0.f;
      #pragma unroll
      for (int q = 0; q < 8; ++q) t += red[f][q];
      projP[s * 32 + f] = t;
    }
  }
}

// ---- persistent GRU: 6 waves, balanced epilogue, conflict-free LDS -----------
__global__ __launch_bounds__(384, 1) void gru_main(
    const float* __restrict__ belief, const int* __restrict__ actions,
    const float* __restrict__ b_hh, const unsigned short* __restrict__ wBf,
    const float* __restrict__ girz, const float* __restrict__ gin,
    unsigned short* __restrict__ hbS, unsigned* __restrict__ cnt) {
  __shared__ unsigned short sA[64 * 512];      // 65536B, a-major frags
  __shared__ float accL2[12672];               // 50688B: [(gam*4+a)*16+m][66]
  __shared__ unsigned short bounce[64 * 74];   // 9472B
  __shared__ float hpL[64 * 66];               // 16896B
  // total 142592B -> 1 wg/CU by LDS

  const int tid = threadIdx.x, w = tid >> 6, lane = tid & 63;
  const int b = blockIdx.x;
  const int sl = b >> 5, g = b & 31;
  const int c0 = sl * 64, seqbase = g * 64;
  const int col0 = lane & 15, quad = lane >> 4;

  // B fragments: 2 N-tiles per wave, register-resident (spill-streams if not)
  bf16x8 bB[32];
  {
    const unsigned short* p0 = wBf + ((size_t)((sl * 12 + 2 * w) * 16) << 9) + lane * 8;
    #pragma unroll
    for (int kt = 0; kt < 32; ++kt) bB[kt] = ld_b128(p0 + ((size_t)kt << 9));
    WAITVM0();
  }

  // hp init: thread owns (s = 6k+w, c = lane)
  #pragma unroll
  for (int k = 0; k < 11; ++k) {
    int s = 6 * k + w;
    if (s < 64) hpL[s * 66 + lane] = belief[((size_t)(seqbase + s) << 9) + c0 + lane];
  }

  for (int j = 0; j < KK; ++j) {
    if (j > 0) {                               // group barrier
      if (tid == 0) {
        const unsigned tgt = 8u * (unsigned)j;
        while (ld_u32_bypass(cnt + g * 32) < tgt) __builtin_amdgcn_s_sleep(1);
      }
      __syncthreads();
    }
    // stage h_j, sl-rotated line order to spread L3 bank/line pressure
    {
      const unsigned short* src = hbS + (size_t)j * SLOT + ((size_t)(g * 64) << 9);
      int line[11];
      bf16x8 tv[11];
      #pragma unroll
      for (int k = 0; k < 11; ++k) line[k] = ((tid + 384 * k) + sl * 512) & 4095;
      #pragma unroll
      for (int k = 0; k < 10; ++k) tv[k] = ld_b128_bypass(src + ((size_t)line[k] << 3));
      const bool ex = (tid < 256);
      if (ex) tv[10] = ld_b128_bypass(src + ((size_t)line[10] << 3));
      WAITVM0();
      #pragma unroll
      for (int k = 0; k < 10; ++k) *(bf16x8*)&sA[(size_t)line[k] << 3] = tv[k];
      if (ex) *(bf16x8*)&sA[(size_t)line[10] << 3] = tv[10];
    }
    __syncthreads();

    // GEMM: 128 MFMA per wave
    f32x4 acc[4][2];
    #pragma unroll
    for (int a = 0; a < 4; ++a) { acc[a][0] = (f32x4){0,0,0,0}; acc[a][1] = (f32x4){0,0,0,0}; }
    #pragma unroll
    for (int kt = 0; kt < 16; ++kt) {
      #pragma unroll
      for (int a = 0; a < 4; ++a) {
        bf16x8 af = *(const bf16x8*)&sA[((a * 16 + kt) << 9) + (lane << 3)];
        acc[a][0] = MFMA16(af, bB[kt], acc[a][0]);
        acc[a][1] = MFMA16(af, bB[16 + kt], acc[a][1]);
      }
    }
    __syncthreads();   // sA dead this step (cls runs post-kernel)

    // publish accs, conflict-free scalar layout (<=2-way everywhere)
    #pragma unroll
    for (int t2 = 0; t2 < 2; ++t2) {
      int nu = w * 2 + t2, gam = nu >> 2, q = nu & 3;
      #pragma unroll
      for (int a = 0; a < 4; ++a)
        #pragma unroll
        for (int r = 0; r < 4; ++r)
          accL2[((gam * 4 + a) * 16 + quad * 4 + r) * 66 + q * 16 + col0] = acc[a][t2][r];
    }
    __syncthreads();

    // balanced epilogue: (s = 6k+w, c = lane)
    #pragma unroll
    for (int k = 0; k < 11; ++k) {
      int s = 6 * k + w;
      if (s < 64) {
        int c = lane, a = s >> 4, m = s & 15;
        int cc = c0 + c;
        float aR = accL2[((a) * 16 + m) * 66 + c];
        float aZ = accL2[((4 + a) * 16 + m) * 66 + c];
        float aN = accL2[((8 + a) * 16 + m) * 66 + c];
        int seq = seqbase + s;
        int tr = seq >> 3, nn = seq & 7, tj = tr + j;
        int ai = (tj < T_DIM) ? actions[tj * 8 + nn] : 7;
        float rg = 1.f / (1.f + __expf(-(aR + girz[(ai << 9) + cc])));
        float zg = 1.f / (1.f + __expf(-(aZ + girz[((8 + ai) << 9) + cc])));
        float pre = gin[(ai << 9) + cc] + rg * (aN + b_hh[1024 + cc]);
        float cand = 1.f - 2.f / (1.f + __expf(2.f * pre));
        float hn = (1.f - zg) * cand + zg * hpL[s * 66 + c];
        hpL[s * 66 + c] = hn;
        bounce[s * 74 + c] = f2b(hn);
      }
    }
    __syncthreads();

    // publish our slice's h_{j+1} frags (kt = 2sl+ktl) to slot j+1 (a-major)
    unsigned short* dst = hbS + (size_t)(j + 1) * SLOT;
    {
      int f = tid >> 6, l = tid & 63;          // f in 0..5
      int a = f >> 1, ktl = f & 1;
      bf16x8 vv = *(const bf16x8*)&bounce[(16 * a + (l & 15)) * 74 + 32 * ktl + (l >> 4) * 8];
      st_b128_bypass(&dst[((size_t)(g * 64 + a * 16 + sl * 2 + ktl) << 9) + (l << 3)], vv);
      if (tid < 128) {
        int i2 = tid + 384;
        int f2 = i2 >> 6, l2 = i2 & 63;
        int a2 = f2 >> 1, ktl2 = f2 & 1;
        bf16x8 v2b = *(const bf16x8*)&bounce[(16 * a2 + (l2 & 15)) * 74 + 32 * ktl2 + (l2 >> 4) * 8];
        st_b128_bypass(&dst[((size_t)(g * 64 + a2 * 16 + sl * 2 + ktl2) << 9) + (l2 << 3)], v2b);
      }
    }
    WAITVM0();                                 // each thread drains its own stores
    __syncthreads();                           // => all wg stores at L3
    if (tid == 0) atomicAdd(cnt + g * 32, 1u);
  }
}

// ---- classifier + loss: 512 blocks x 4 waves, atomic-free --------------------
__global__ __launch_bounds__(256, 1) void cls(
    const unsigned short* __restrict__ hbS, const unsigned short* __restrict__ wQf,
    const int* __restrict__ neg_inds, const float* __restrict__ b1,
    const float* __restrict__ W2, const float* __restrict__ b2,
    const float* __restrict__ projP, const unsigned char* __restrict__ maskb,
    float* __restrict__ parts) {
  __shared__ float red[4][4];
  const int g = blockIdx.x >> 4, jq = blockIdx.x & 15;
  const int w = threadIdx.x >> 6, lane = threadIdx.x & 63;
  const int col0 = lane & 15, quad = lane >> 4;
  const int a = w, j = jq + 1;
  const unsigned short* hsrc = hbS + (size_t)j * SLOT + ((size_t)(g * 64 + a * 16) << 9);
  const unsigned short* qp = wQf + lane * 8;
  f32x4 acc0 = {0,0,0,0}, acc1 = {0,0,0,0};
  #pragma unroll
  for (int kt = 0; kt < 16; ++kt) {
    bf16x8 af = *(const bf16x8*)&hsrc[((size_t)kt << 9) + lane * 8];
    acc0 = MFMA16(af, *(const bf16x8*)(qp + ((size_t)kt << 9)), acc0);
    acc1 = MFMA16(af, *(const bf16x8*)(qp + ((size_t)(16 + kt) << 9)), acc1);
  }
  float b1v0 = b1[col0], b1v1 = b1[col0 + 16];
  float w2v0 = W2[col0], w2v1 = W2[col0 + 16], b2v = b2[0];
  float wj = (jq == 0) ? 5.f : (jq == 1) ? 4.f : (jq < 4) ? 3.f : (jq < 8) ? 2.f : 1.f;
  float sumP = 0.f, cntP = 0.f, sumN = 0.f, cntN = 0.f;
  #pragma unroll
  for (int r = 0; r < 4; ++r) {
    int seq = g * 64 + 16 * a + quad * 4 + r;
    int t = seq >> 3, nn = seq & 7;
    unsigned mb = maskb[(t << 7) + (jq << 3) + nn];
    float pp0 = 0.f, pp1 = 0.f, pn0 = 0.f, pn1 = 0.f;
    if (mb) {
      int sp = seq + j * 8;
      pp0 = projP[(sp << 5) + col0];  pp1 = projP[(sp << 5) + 16 + col0];
      int ni = neg_inds[sp];
      pn0 = projP[(ni << 5) + col0];  pn1 = projP[(ni << 5) + 16 + col0];
    }
    float a0v = acc0[r] + b1v0, a1v = acc1[r] + b1v1;
    float pl = fmaxf(a0v + pp0, 0.f) * w2v0 + fmaxf(a1v + pp1, 0.f) * w2v1;
    float nl = fmaxf(a0v + pn0, 0.f) * w2v0 + fmaxf(a1v + pn1, 0.f) * w2v1;
    #pragma unroll
    for (int d = 1; d < 16; d <<= 1) { pl += __shfl_xor(pl, d, 64); nl += __shfl_xor(nl, d, 64); }
    if (col0 == 0 && mb) {
      if (mb & 1u) {
        float x = -(pl + b2v);
        sumP += wj * (fmaxf(x, 0.f) + __logf(1.f + __expf(-fabsf(x))));
        cntP += 1.f;
      }
      if (mb & 2u) {
        float x = (nl + b2v);
        sumN += wj * (fmaxf(x, 0.f) + __logf(1.f + __expf(-fabsf(x))));
        cntN += 1.f;
      }
    }
  }
  #pragma unroll
  for (int d = 16; d < 64; d <<= 1) {
    sumP += __shfl_xor(sumP, d, 64); cntP += __shfl_xor(cntP, d, 64);
    sumN += __shfl_xor(sumN, d, 64); cntN += __shfl_xor(cntN, d, 64);
  }
  if (lane == 0) { red[w][0] = sumP; red[w][1] = cntP; red[w][2] = sumN; red[w][3] = cntN; }
  __syncthreads();
  if (threadIdx.x < 4)
    parts[blockIdx.x * 4 + threadIdx.x] =
        red[0][threadIdx.x] + red[1][threadIdx.x] + red[2][threadIdx.x] + red[3][threadIdx.x];
}

__global__ __launch_bounds__(256, 1) void fin(const float* __restrict__ parts,
                                              float* __restrict__ out) {
  __shared__ float red[4][4];
  const int tid = threadIdx.x;
  float v0 = 0.f, v1 = 0.f, v2 = 0.f, v3 = 0.f;
  for (int i = tid; i < 512; i += 256) {
    v0 += parts[i * 4 + 0]; v1 += parts[i * 4 + 1];
    v2 += parts[i * 4 + 2]; v3 += parts[i * 4 + 3];
  }
  #pragma unroll
  for (int d = 1; d < 64; d <<= 1) {
    v0 += __shfl_xor(v0, d, 64); v1 += __shfl_xor(v1, d, 64);
    v2 += __shfl_xor(v2, d, 64); v3 += __shfl_xor(v3, d, 64);
  }
  if ((tid & 63) == 0) {
    int w = tid >> 6;
    red[w][0] = v0; red[w][1] = v1; red[w][2] = v2; red[w][3] = v3;
  }
  __syncthreads();
  if (tid == 0) {
    float sP = red[0][0] + red[1][0] + red[2][0] + red[3][0];
    float cP = red[0][1] + red[1][1] + red[2][1] + red[3][1];
    float sN = red[0][2] + red[1][2] + red[2][2] + red[3][2];
    float cN = red[0][3] + red[1][3] + red[2][3] + red[3][3];
    out[0] = (sP / fmaxf(cP, 1.f) + sN / fmaxf(cN, 1.f)) * 0.1f;
  }
}

extern "C" void kernel_launch(void* const* d_in, const int* in_sizes, int n_in,
                              void* d_out, int out_size, void* d_ws, size_t ws_size,
                              hipStream_t stream) {
  const float* vision  = (const float*)d_in[0];
  const float* belief  = (const float*)d_in[1];
  const int*   actions = (const int*)d_in[2];
  const int*   envz    = (const int*)d_in[3];
  const int*   negi    = (const int*)d_in[4];
  const float* emb     = (const float*)d_in[5];
  const float* W_ih    = (const float*)d_in[6];
  const float* W_hh    = (const float*)d_in[7];
  const float* b_ih    = (const float*)d_in[8];
  const float* b_hh    = (const float*)d_in[9];
  const float* W1      = (const float*)d_in[10];
  const float* b1      = (const float*)d_in[11];
  const float* W2      = (const float*)d_in[12];
  const float* b2      = (const float*)d_in[13];

  char* ws = (char*)d_ws;
  unsigned*       cnt   = (unsigned*)(ws + 0);               // 1024 ints (4KB)
  float*          parts = (float*)(ws + 4096);               // 512 x 4 floats
  unsigned short* wBf   = (unsigned short*)(ws + 12288);     // 1572864 B
  unsigned short* wQf   = (unsigned short*)(ws + 1585152);   // 32768 B
  float*          girz  = (float*)(ws + 1617920);            // 32768 B
  float*          gin   = (float*)(ws + 1650688);            // 16384 B
  float*          projP = (float*)(ws + 1667072);            // 262144 B
  unsigned char*  maskb = (unsigned char*)(ws + 1929216);    // 32768 B
  unsigned short* hbS   = (unsigned short*)(ws + 1961984);   // 17 x 2097152 B

  prep<<<3457, 256, 0, stream>>>(W_hh, W1, emb, W_ih, b_ih, b_hh, vision, envz,
                                 belief, wBf, wQf, girz, gin, projP, maskb,
                                 hbS, cnt);
  gru_main<<<256, 384, 0, stream>>>(belief, actions, b_hh, wBf, girz, gin,
                                    hbS, cnt);
  cls<<<512, 256, 0, stream>>>(hbS, wQf, negi, b1, W2, b2, projP, maskb, parts);
  fin<<<1, 256, 0, stream>>>(parts, (float*)d_out);
}